// Round 11
// baseline (806.917 us; speedup 1.0000x reference)
//
#include <hip/hip_runtime.h>
#include <stdint.h>

#define B_    4
#define S_    1024
#define E_    1024
#define H_    16
#define NE_   8
#define DFF_  4096
#define NT_   4096          // B_*S_ tokens
#define QS_   3072          // fused qkv row stride
#define ROWCAP9_ 13440      // 8 experts padded (<=9216) + 4096 shared + slack

typedef unsigned short u16;
typedef short bf16x8 __attribute__((ext_vector_type(8)));
typedef float f32x4 __attribute__((ext_vector_type(4)));

__device__ __forceinline__ float bf2f(u16 u){ unsigned v = ((unsigned)u) << 16; return __builtin_bit_cast(float, v); }
__device__ __forceinline__ u16 f2bf(float f){ unsigned x = __builtin_bit_cast(unsigned, f); return (u16)((x + 0x7FFFu + ((x >> 16) & 1u)) >> 16); }
__device__ __forceinline__ float gelu_f(float x){ return 0.5f * x * (1.f + erff(x * 0.70710678118f)); }

// async global->LDS, 16B per lane; LDS dest = wave-uniform base + lane*16
__device__ __forceinline__ void gl_lds16(const u16* g, u16* l){
  __builtin_amdgcn_global_load_lds((__attribute__((address_space(1))) void*)(const_cast<u16*>(g)),
                                   (__attribute__((address_space(3))) void*)(l), 16, 0, 0);
}

// LDS XOR swizzle (32-u16 rows, 4 slots of 16B) — conflict-free, verified r4 (13.2M -> 0).
#define KSW32(l)   ((((l) & 3) ^ (((l) >> 3) & 3)) << 3)
#define FRAGOFF(l) (((l) & 15) * 32 + (((((l) >> 4) ^ (((l) >> 1) & 3))) << 3))

// counted vmcnt: future-tile loads stay in flight across the barrier (T4).
// NO sched_barrier — m141: order-pinning regresses to ~510 TF.
#define VMCNT(n)   asm volatile("s_waitcnt vmcnt(" #n ")" ::: "memory")

// ---------------- LayerNorm: f32 in -> bf16 out ----------------
__launch_bounds__(256)
__global__ void ln_kernel(const float* __restrict__ x, const float* __restrict__ g,
                          const float* __restrict__ be, u16* __restrict__ out)
{
  const int row = blockIdx.x;
  const float4 v = ((const float4*)(x + (size_t)row * E_))[threadIdx.x];
  float s = v.x + v.y + v.z + v.w;
  #pragma unroll
  for(int mm = 32; mm >= 1; mm >>= 1) s += __shfl_xor(s, mm);
  __shared__ float red[8];
  const int wid = threadIdx.x >> 6;
  if((threadIdx.x & 63) == 0) red[wid] = s;
  __syncthreads();
  const float mean = (red[0] + red[1] + red[2] + red[3]) * (1.0f / E_);
  const float d0 = v.x - mean, d1 = v.y - mean, d2 = v.z - mean, d3 = v.w - mean;
  float q2 = d0*d0 + d1*d1 + d2*d2 + d3*d3;
  #pragma unroll
  for(int mm = 32; mm >= 1; mm >>= 1) q2 += __shfl_xor(q2, mm);
  if((threadIdx.x & 63) == 0) red[4 + wid] = q2;
  __syncthreads();
  const float var = (red[4] + red[5] + red[6] + red[7]) * (1.0f / E_);
  const float rs = rsqrtf(var + 1e-5f);
  const float4 gg = ((const float4*)g)[threadIdx.x];
  const float4 bb = ((const float4*)be)[threadIdx.x];
  ushort4 o;
  o.x = f2bf(d0 * rs * gg.x + bb.x);
  o.y = f2bf(d1 * rs * gg.y + bb.y);
  o.z = f2bf(d2 * rs * gg.z + bb.z);
  o.w = f2bf(d3 * rs * gg.w + bb.w);
  ((ushort4*)(out + (size_t)row * E_))[threadIdx.x] = o;
}

// ---------------- fused LayerNorm2 + router (one block per token) ----------------
__launch_bounds__(256)
__global__ void ln_router_kernel(const float* __restrict__ x, const float* __restrict__ g,
                                 const float* __restrict__ be, u16* __restrict__ out,
                                 const float* __restrict__ wg,
                                 float* __restrict__ probs, float* __restrict__ tkgate,
                                 int* __restrict__ tkidx, int* __restrict__ counts)
{
  const int row = blockIdx.x;
  const int tid = threadIdx.x, lane = tid & 63, wid = tid >> 6;
  const float4 v = ((const float4*)(x + (size_t)row * E_))[tid];
  float s = v.x + v.y + v.z + v.w;
  #pragma unroll
  for(int mm = 32; mm >= 1; mm >>= 1) s += __shfl_xor(s, mm);
  __shared__ float red[8];
  __shared__ float part[4][8];
  if(lane == 0) red[wid] = s;
  __syncthreads();
  const float mean = (red[0] + red[1] + red[2] + red[3]) * (1.0f / E_);
  const float d0 = v.x - mean, d1 = v.y - mean, d2 = v.z - mean, d3 = v.w - mean;
  float q2 = d0*d0 + d1*d1 + d2*d2 + d3*d3;
  #pragma unroll
  for(int mm = 32; mm >= 1; mm >>= 1) q2 += __shfl_xor(q2, mm);
  if(lane == 0) red[4 + wid] = q2;
  __syncthreads();
  const float var = (red[4] + red[5] + red[6] + red[7]) * (1.0f / E_);
  const float rs = rsqrtf(var + 1e-5f);
  const float4 gg = ((const float4*)g)[tid];
  const float4 bb = ((const float4*)be)[tid];
  ushort4 o;
  o.x = f2bf(d0 * rs * gg.x + bb.x);
  o.y = f2bf(d1 * rs * gg.y + bb.y);
  o.z = f2bf(d2 * rs * gg.z + bb.z);
  o.w = f2bf(d3 * rs * gg.w + bb.w);
  ((ushort4*)(out + (size_t)row * E_))[tid] = o;
  // router partials on bf16-rounded h2 (bit-identical to reading h2 back)
  const float h0 = bf2f(o.x), h1 = bf2f(o.y), h2v = bf2f(o.z), h3 = bf2f(o.w);
  float a[8];
  #pragma unroll
  for(int e = 0; e < 8; e++) a[e] = 0.f;
  const float* wr = wg + (size_t)(tid * 4) * NE_;
  #pragma unroll
  for(int j = 0; j < 4; j++){
    const float hj = (j == 0) ? h0 : (j == 1) ? h1 : (j == 2) ? h2v : h3;
    const float4 w0 = *(const float4*)(wr + j * NE_);
    const float4 w1 = *(const float4*)(wr + j * NE_ + 4);
    a[0] += hj * w0.x; a[1] += hj * w0.y; a[2] += hj * w0.z; a[3] += hj * w0.w;
    a[4] += hj * w1.x; a[5] += hj * w1.y; a[6] += hj * w1.z; a[7] += hj * w1.w;
  }
  #pragma unroll
  for(int mm = 1; mm < 64; mm <<= 1)
    #pragma unroll
    for(int e = 0; e < 8; e++) a[e] += __shfl_xor(a[e], mm);
  if(lane == 0)
    #pragma unroll
    for(int e = 0; e < 8; e++) part[wid][e] = a[e];
  __syncthreads();
  if(tid == 0){
    float lg[8];
    #pragma unroll
    for(int e = 0; e < 8; e++) lg[e] = part[0][e] + part[1][e] + part[2][e] + part[3][e];
    float mx = lg[0];
    #pragma unroll
    for(int e = 1; e < 8; e++) mx = fmaxf(mx, lg[e]);
    float se = 0.f, ex[8];
    #pragma unroll
    for(int e = 0; e < 8; e++){ ex[e] = expf(lg[e] - mx); se += ex[e]; }
    const float inv = 1.f / se;
    float* pr = probs + (size_t)row * 8;
    #pragma unroll
    for(int e = 0; e < 8; e++) pr[e] = ex[e] * inv;
    int i1 = 0; float v1 = lg[0];
    #pragma unroll
    for(int e = 1; e < 8; e++) if(lg[e] > v1){ v1 = lg[e]; i1 = e; }
    int i2 = -1; float v2 = -3.4e38f;
    #pragma unroll
    for(int e = 0; e < 8; e++) if(e != i1 && lg[e] > v2){ v2 = lg[e]; i2 = e; }
    const float t = expf(v2 - v1);
    tkidx[row*2] = i1; tkidx[row*2+1] = i2;
    tkgate[row*2] = 1.f / (1.f + t); tkgate[row*2+1] = t / (1.f + t);
    atomicAdd(&counts[i1], 1); atomicAdd(&counts[i2], 1);
  }
}

// ------------- transpose core: W (KxN f32) -> WT (NxK bf16) -------------
__device__ __forceinline__ void transpose_body(const float* __restrict__ W, u16* __restrict__ WT, int K, int N)
{
  __shared__ __align__(16) u16 t[64][72];
  const int k0 = blockIdx.x * 64, n0 = blockIdx.y * 64;
  const int tid = threadIdx.x;
  const int kr = tid >> 2;
  const int nc = (tid & 3) * 4;
  #pragma unroll
  for(int p = 0; p < 4; p++){
    float4 v = *(const float4*)(W + (size_t)(k0 + kr) * N + n0 + nc + p * 16);
    t[nc + p*16 + 0][kr] = f2bf(v.x);
    t[nc + p*16 + 1][kr] = f2bf(v.y);
    t[nc + p*16 + 2][kr] = f2bf(v.z);
    t[nc + p*16 + 3][kr] = f2bf(v.w);
  }
  __syncthreads();
  const int nr = tid >> 3;
  const int kg = (tid & 7) * 8;
  #pragma unroll
  for(int p = 0; p < 2; p++){
    const int nn = nr + p * 32;
    unsigned u0 = t[nn][kg+0], u1 = t[nn][kg+1], u2 = t[nn][kg+2], u3 = t[nn][kg+3];
    unsigned u4 = t[nn][kg+4], u5 = t[nn][kg+5], u6 = t[nn][kg+6], u7 = t[nn][kg+7];
    uint4 o;
    o.x = u0 | (u1 << 16); o.y = u2 | (u3 << 16); o.z = u4 | (u5 << 16); o.w = u6 | (u7 << 16);
    *(uint4*)(WT + (size_t)(n0 + nn) * K + k0 + kg) = o;
  }
}

__launch_bounds__(256)
__global__ void transpose_kernel(const float* __restrict__ W, u16* __restrict__ WT, int K, int N)
{ transpose_body(W, WT, K, N); }

// 4 attention weights (1024x1024 each) in one launch, z selects
__launch_bounds__(256)
__global__ void transpose4_kernel(const float* wq, const float* wk, const float* wv, const float* wo,
                                  u16* __restrict__ WT)
{
  const float* W = (blockIdx.z == 0) ? wq : (blockIdx.z == 1) ? wk : (blockIdx.z == 2) ? wv : wo;
  transpose_body(W, WT + (size_t)blockIdx.z * E_ * E_, E_, E_);
}

// 9-panel transpose: z<8 -> ew + z*K*N ; z==8 -> sw (shared as expert 8)
__launch_bounds__(256)
__global__ void transpose9_kernel(const float* __restrict__ ew, const float* __restrict__ sw,
                                  u16* __restrict__ WT, int K, int N)
{
  const float* W = (blockIdx.z < 8) ? (ew + (size_t)blockIdx.z * K * N) : sw;
  transpose_body(W, WT + (size_t)blockIdx.z * K * N, K, N);
}

// ---------------- prep: bcat, router init, 9-expert bias tables ----------------
__global__ void prep_kernel(const float* __restrict__ bq, const float* __restrict__ bk,
                            const float* __restrict__ bv, float* __restrict__ bcat,
                            int* __restrict__ counts, int* __restrict__ rowlist,
                            const float* __restrict__ eb1, const float* __restrict__ sb1,
                            float* __restrict__ b9up,
                            const float* __restrict__ eb2, const float* __restrict__ sb2,
                            float* __restrict__ b9dn)
{
  const int stride = gridDim.x * 256;
  for(int i = blockIdx.x * 256 + threadIdx.x; i < 9 * DFF_; i += stride){
    b9up[i] = (i < 8 * DFF_) ? eb1[i] : sb1[i - 8 * DFF_];
    if(i < 9 * E_)   b9dn[i] = (i < 8 * E_) ? eb2[i] : sb2[i - 8 * E_];
    if(i < QS_)      bcat[i] = (i < E_) ? bq[i] : (i < 2*E_) ? bk[i - E_] : bv[i - 2*E_];
    if(i < 16)       counts[i] = 0;
    if(i < ROWCAP9_) rowlist[i] = -1;
  }
}

// ---------------- route: scan + build + aux in ONE single-block kernel ----------------
__launch_bounds__(256)
__global__ void route_kernel(const int* __restrict__ counts, const int* __restrict__ tkidx,
                             const float* __restrict__ tkgate, const float* __restrict__ probs,
                             int* __restrict__ aoff, int* __restrict__ rowlist,
                             float* __restrict__ rowgate, float* __restrict__ outaux, int addShared)
{
  __shared__ int cur[8];
  __shared__ int aoffs[10];
  __shared__ float part[4][8];
  const int tid = threadIdx.x, lane = tid & 63, wid = tid >> 6;
  if(tid == 0){
    int o = 0;
    for(int e = 0; e < 8; e++){ aoffs[e] = o; cur[e] = o; o += ((counts[e] + 127) >> 7) << 7; }
    aoffs[8] = o; aoffs[9] = o + (addShared ? NT_ : 0);
    for(int e = 0; e < 10; e++) aoff[e] = aoffs[e];
  }
  __syncthreads();
  for(int t = tid; t < NT_; t += 256){
    #pragma unroll
    for(int kk = 0; kk < 2; kk++){
      const int e = tkidx[t*2 + kk];
      const int pos = atomicAdd(&cur[e], 1);
      rowlist[pos] = t; rowgate[pos] = tkgate[t*2 + kk];
    }
    if(addShared){ rowlist[aoffs[8] + t] = t; rowgate[aoffs[8] + t] = 1.f; }
  }
  // aux loss
  float a[8];
  #pragma unroll
  for(int e = 0; e < 8; e++) a[e] = 0.f;
  for(int t = tid; t < NT_; t += 256){
    const float* p = probs + (size_t)t * 8;
    #pragma unroll
    for(int e = 0; e < 8; e++) a[e] += p[e];
  }
  #pragma unroll
  for(int mm = 1; mm < 64; mm <<= 1)
    #pragma unroll
    for(int e = 0; e < 8; e++) a[e] += __shfl_xor(a[e], mm);
  if(lane == 0)
    #pragma unroll
    for(int e = 0; e < 8; e++) part[wid][e] = a[e];
  __syncthreads();
  if(tid == 0){
    float aux = 0.f;
    for(int e = 0; e < 8; e++){
      const float P = (part[0][e] + part[1][e] + part[2][e] + part[3][e]) / (float)NT_;
      const float f = (float)counts[e] / (float)NT_;
      aux += P * f;
    }
    outaux[0] = (float)NE_ * aux;
  }
}

// ======== GEMM BM=128, BN=128, BK=64 (r3 structure + swizzle) ========
// MODE 0: outB = bf16(acc+bias)        (fused qkv)
// MODE 1: outB = bf16(gelu(acc+bias))  (legacy shared FFN up)
template<int MODE>
__launch_bounds__(256)
__global__ void gemm_kernel(const u16* __restrict__ A, const u16* __restrict__ Bt,
                            int N, int Kd, const float* __restrict__ bias,
                            u16* __restrict__ outB)
{
  __shared__ __align__(16) u16 As0[4096], Bs0[4096], As1[4096], Bs1[4096];
  const int tid = threadIdx.x, lane = tid & 63, wid = tid >> 6;
  const int wm = wid >> 1, wn = wid & 1;
  const int tm = blockIdx.y * 128, tn = blockIdx.x * 128;

  const f32x4 zero = {0.f, 0.f, 0.f, 0.f};
  f32x4 acc[4][4];
  #pragma unroll
  for(int m = 0; m < 4; m++)
    #pragma unroll
    for(int n = 0; n < 4; n++) acc[m][n] = zero;

  const int ksw = KSW32(lane);
  const u16* gA0 = A  + (size_t)(tm + wid*32 + (lane >> 2)) * Kd + ksw;
  const u16* gA1 = gA0 + (size_t)16 * Kd;
  const u16* gB0 = Bt + (size_t)(tn + wid*32 + (lane >> 2)) * Kd + ksw;
  const u16* gB1 = gB0 + (size_t)16 * Kd;
  u16* lA0 = As0 + wid*1024; u16* lA1 = lA0 + 512;
  u16* lB0 = Bs0 + wid*1024; u16* lB1 = lB0 + 512;
  u16* lA0b = As1 + wid*1024; u16* lA1b = lA0b + 512;
  u16* lB0b = Bs1 + wid*1024; u16* lB1b = lB0b + 512;
  const int fo = FRAGOFF(lane);
  const int fA = wm * 2048, fB = wn * 2048;

  for(int k0 = 0; k0 < Kd; k0 += 64){
    __syncthreads();
    gl_lds16(gA0 + k0, lA0);  gl_lds16(gA1 + k0, lA1);
    gl_lds16(gB0 + k0, lB0);  gl_lds16(gB1 + k0, lB1);
    gl_lds16(gA0 + k0+32, lA0b); gl_lds16(gA1 + k0+32, lA1b);
    gl_lds16(gB0 + k0+32, lB0b); gl_lds16(gB1 + k0+32, lB1b);
    __syncthreads();
    bf16x8 aF[4], bF[4];
    #pragma unroll
    for(int m = 0; m < 4; m++) aF[m] = *(const bf16x8*)(As0 + fA + m*512 + fo);
    #pragma unroll
    for(int n = 0; n < 4; n++) bF[n] = *(const bf16x8*)(Bs0 + fB + n*512 + fo);
    #pragma unroll
    for(int m = 0; m < 4; m++)
      #pragma unroll
      for(int n = 0; n < 4; n++)
        acc[m][n] = __builtin_amdgcn_mfma_f32_16x16x32_bf16(aF[m], bF[n], acc[m][n], 0, 0, 0);
    #pragma unroll
    for(int m = 0; m < 4; m++) aF[m] = *(const bf16x8*)(As1 + fA + m*512 + fo);
    #pragma unroll
    for(int n = 0; n < 4; n++) bF[n] = *(const bf16x8*)(Bs1 + fB + n*512 + fo);
    #pragma unroll
    for(int m = 0; m < 4; m++)
      #pragma unroll
      for(int n = 0; n < 4; n++)
        acc[m][n] = __builtin_amdgcn_mfma_f32_16x16x32_bf16(aF[m], bF[n], acc[m][n], 0, 0, 0);
  }

  #pragma unroll
  for(int m = 0; m < 4; m++){
    const int row = tm + wm*64 + m*16 + ((lane >> 4) << 2);
    #pragma unroll
    for(int n = 0; n < 4; n++){
      const int col = tn + wn*64 + n*16 + (lane & 15);
      const float bc = bias[col];
      #pragma unroll
      for(int r = 0; r < 4; r++){
        const float v = acc[m][n][r] + bc;
        const size_t idx = (size_t)(row + r) * N + col;
        if constexpr(MODE == 0) outB[idx] = f2bf(v);
        else outB[idx] = f2bf(gelu_f(v));
      }
    }
  }
}

// ======== GEMM BM=64, BN=128, BK=64 (o-proj / legacy FFN-down) ========
// MODE 2: outF = resid + acc + bias
// MODE 3: outF += acc + bias
template<int MODE>
__launch_bounds__(256)
__global__ void gemm64_kernel(const u16* __restrict__ A, const u16* __restrict__ Bt,
                              int N, int Kd, const float* __restrict__ bias,
                              float* __restrict__ outF, const float* __restrict__ resid)
{
  __shared__ __align__(16) u16 As0[2048], As1[2048], Bs0[4096], Bs1[4096];
  const int tid = threadIdx.x, lane = tid & 63, wid = tid >> 6;
  const int wm = wid >> 1, wn = wid & 1;
  const int tm = blockIdx.y * 64, tn = blockIdx.x * 128;

  const f32x4 zero = {0.f, 0.f, 0.f, 0.f};
  f32x4 acc[2][4];
  #pragma unroll
  for(int m = 0; m < 2; m++)
    #pragma unroll
    for(int n = 0; n < 4; n++) acc[m][n] = zero;

  const int ksw = KSW32(lane);
  const u16* gA = A + (size_t)(tm + wid*16 + (lane >> 2)) * Kd + ksw;
  const u16* gB0 = Bt + (size_t)(tn + wid*32 + (lane >> 2)) * Kd + ksw;
  const u16* gB1 = gB0 + (size_t)16 * Kd;
  u16* lA  = As0 + wid*512;  u16* lAb = As1 + wid*512;
  u16* lB0 = Bs0 + wid*1024; u16* lB1 = lB0 + 512;
  u16* lB0b = Bs1 + wid*1024; u16* lB1b = lB0b + 512;
  const int fo = FRAGOFF(lane);
  const int fA = wm * 1024, fB = wn * 2048;

  for(int k0 = 0; k0 < Kd; k0 += 64){
    __syncthreads();
    gl_lds16(gA + k0, lA);
    gl_lds16(gB0 + k0, lB0); gl_lds16(gB1 + k0, lB1);
    gl_lds16(gA + k0+32, lAb);
    gl_lds16(gB0 + k0+32, lB0b); gl_lds16(gB1 + k0+32, lB1b);
    __syncthreads();
    bf16x8 aF[2], bF[4];
    #pragma unroll
    for(int m = 0; m < 2; m++) aF[m] = *(const bf16x8*)(As0 + fA + m*512 + fo);
    #pragma unroll
    for(int n = 0; n < 4; n++) bF[n] = *(const bf16x8*)(Bs0 + fB + n*512 + fo);
    #pragma unroll
    for(int m = 0; m < 2; m++)
      #pragma unroll
      for(int n = 0; n < 4; n++)
        acc[m][n] = __builtin_amdgcn_mfma_f32_16x16x32_bf16(aF[m], bF[n], acc[m][n], 0, 0, 0);
    #pragma unroll
    for(int m = 0; m < 2; m++) aF[m] = *(const bf16x8*)(As1 + fA + m*512 + fo);
    #pragma unroll
    for(int n = 0; n < 4; n++) bF[n] = *(const bf16x8*)(Bs1 + fB + n*512 + fo);
    #pragma unroll
    for(int m = 0; m < 2; m++)
      #pragma unroll
      for(int n = 0; n < 4; n++)
        acc[m][n] = __builtin_amdgcn_mfma_f32_16x16x32_bf16(aF[m], bF[n], acc[m][n], 0, 0, 0);
  }

  #pragma unroll
  for(int m = 0; m < 2; m++){
    const int row = tm + wm*32 + m*16 + ((lane >> 4) << 2);
    #pragma unroll
    for(int n = 0; n < 4; n++){
      const int col = tn + wn*64 + n*16 + (lane & 15);
      const float bc = bias[col];
      #pragma unroll
      for(int r = 0; r < 4; r++){
        const float v = acc[m][n][r] + bc;
        const size_t idx = (size_t)(row + r) * N + col;
        if constexpr(MODE == 2) outF[idx] = resid[idx] + v;
        else outF[idx] += v;
      }
    }
  }
}

// ---------------- flash attention over fused qkv buffer [tok][3072] ----------------
__launch_bounds__(256)
__global__ void attn_kernel(const u16* __restrict__ qkv, u16* __restrict__ ctx)
{
  __shared__ __align__(16) u16 Ks[64 * 64];
  __shared__ __align__(16) u16 Vt[64 * 72];
  __shared__ __align__(16) u16 Ps[64 * 72];
  const int tid = threadIdx.x, lane = tid & 63, wid = tid >> 6;
  const int bh = blockIdx.y, bb = bh >> 4, hh = bh & 15;
  const int q0 = blockIdx.x * 64;
  const size_t tok0 = (size_t)bb * S_;
  const int hcol = hh * 64;

  bf16x8 aQ0, aQ1;
  {
    const u16* qp = qkv + (tok0 + q0 + wid*16 + (lane & 15)) * QS_ + hcol + ((lane >> 4) << 3);
    aQ0 = *(const bf16x8*)qp;
    aQ1 = *(const bf16x8*)(qp + 32);
  }
  const f32x4 zero = {0.f, 0.f, 0.f, 0.f};
  f32x4 accO[4]; float mrow[4], lrow[4];
  #pragma unroll
  for(int n = 0; n < 4; n++) accO[n] = zero;
  #pragma unroll
  for(int r = 0; r < 4; r++){ mrow[r] = -1e30f; lrow[r] = 0.f; }
  const float sc = 0.125f * 1.44269504f;
  const int ksw8 = (((lane & 7) ^ ((lane >> 3) & 7)) << 3);

  for(int kv0 = 0; kv0 < S_; kv0 += 64){
    __syncthreads();
    {
      const u16* gp = qkv + (tok0 + kv0 + wid*16 + (lane >> 3)) * QS_ + 1024 + hcol + ksw8;
      gl_lds16(gp, Ks + (wid*16) * 64);
      gl_lds16(gp + (size_t)8 * QS_, Ks + (wid*16 + 8) * 64);
    }
    {
      #pragma unroll
      for(int i = 0; i < 2; i++){
        const int tok = (tid >> 3) + i * 32;
        const int d0 = (tid & 7) << 3;
        bf16x8 vv = *(const bf16x8*)(qkv + (tok0 + kv0 + tok) * QS_ + 2048 + hcol + d0);
        #pragma unroll
        for(int j = 0; j < 8; j++) Vt[(d0 + j) * 72 + tok] = (u16)vv[j];
      }
    }
    __syncthreads();
    f32x4 sf[4];
    #pragma unroll
    for(int n = 0; n < 4; n++){
      const int rb = n*16 + (lane & 15);
      bf16x8 b0 = *(const bf16x8*)(Ks + rb*64 + ((((lane >> 4)    ) ^ (lane & 7)) << 3));
      bf16x8 b1 = *(const bf16x8*)(Ks + rb*64 + ((((lane >> 4) + 4) ^ (lane & 7)) << 3));
      f32x4 t = zero;
      t = __builtin_amdgcn_mfma_f32_16x16x32_bf16(aQ0, b0, t, 0, 0, 0);
      t = __builtin_amdgcn_mfma_f32_16x16x32_bf16(aQ1, b1, t, 0, 0, 0);
      sf[n] = t;
    }
    #pragma unroll
    for(int r = 0; r < 4; r++){
      const float s0 = sf[0][r]*sc, s1 = sf[1][r]*sc, s2 = sf[2][r]*sc, s3 = sf[3][r]*sc;
      float mx = fmaxf(fmaxf(s0, s1), fmaxf(s2, s3));
      #pragma unroll
      for(int mm = 1; mm < 16; mm <<= 1) mx = fmaxf(mx, __shfl_xor(mx, mm));
      const float mnew = fmaxf(mrow[r], mx);
      const float resc = exp2f(mrow[r] - mnew);
      mrow[r] = mnew;
      const float p0 = exp2f(s0 - mnew), p1 = exp2f(s1 - mnew);
      const float p2 = exp2f(s2 - mnew), p3 = exp2f(s3 - mnew);
      float ps = p0 + p1 + p2 + p3;
      #pragma unroll
      for(int mm = 1; mm < 16; mm <<= 1) ps += __shfl_xor(ps, mm);
      lrow[r] = lrow[r] * resc + ps;
      #pragma unroll
      for(int n = 0; n < 4; n++) accO[n][r] *= resc;
      const int prow = wid*16 + ((lane >> 4) << 2) + r;
      Ps[prow*72 +      (lane & 15)] = f2bf(p0);
      Ps[prow*72 + 16 + (lane & 15)] = f2bf(p1);
      Ps[prow*72 + 32 + (lane & 15)] = f2bf(p2);
      Ps[prow*72 + 48 + (lane & 15)] = f2bf(p3);
    }
    bf16x8 pa0 = *(const bf16x8*)(Ps + (wid*16 + (lane & 15)) * 72 + ((lane >> 4) << 3));
    bf16x8 pa1 = *(const bf16x8*)(Ps + (wid*16 + (lane & 15)) * 72 + 32 + ((lane >> 4) << 3));
    #pragma unroll
    for(int n = 0; n < 4; n++){
      bf16x8 b0 = *(const bf16x8*)(Vt + (n*16 + (lane & 15)) * 72 + ((lane >> 4) << 3));
      bf16x8 b1 = *(const bf16x8*)(Vt + (n*16 + (lane & 15)) * 72 + 32 + ((lane >> 4) << 3));
      accO[n] = __builtin_amdgcn_mfma_f32_16x16x32_bf16(pa0, b0, accO[n], 0, 0, 0);
      accO[n] = __builtin_amdgcn_mfma_f32_16x16x32_bf16(pa1, b1, accO[n], 0, 0, 0);
    }
  }
  const size_t cbase = tok0 * E_ + hcol;
  #pragma unroll
  for(int n = 0; n < 4; n++)
    #pragma unroll
    for(int r = 0; r < 4; r++){
      const int row = q0 + wid*16 + ((lane >> 4) << 2) + r;
      const int col = n*16 + (lane & 15);
      ctx[cbase + (size_t)row * E_ + col] = f2bf(accO[n][r] / lrow[r]);
    }
}

// ---- upmoe: gathered rows -> gelu hidden; 9 experts (8 routed + shared) ----
__launch_bounds__(256)
__global__ void upmoe_kernel(const u16* __restrict__ Ah2, const u16* __restrict__ W1T,
                             const float* __restrict__ b9up,
                             const int* __restrict__ rowlist, const int* __restrict__ aoff,
                             u16* __restrict__ ehid)
{
  const int rowTile = blockIdx.y * 128;
  if(rowTile >= aoff[9]) return;
  int e = 0;
  #pragma unroll
  for(int i = 1; i <= 8; i++) if(rowTile >= aoff[i]) e = i;
  __shared__ __align__(16) u16 As0[4096], Bs0[4096], As1[4096], Bs1[4096];
  const int tid = threadIdx.x, lane = tid & 63, wid = tid >> 6;
  const int wm = wid >> 1, wn = wid & 1;
  const int tn = blockIdx.x * 128;
  const u16* Bt = W1T + (size_t)e * DFF_ * E_;

  const int r0 = rowTile + wid*32 + (lane >> 2);
  int t0 = rowlist[r0];      if(t0 < 0) t0 = 0;
  int t1 = rowlist[r0 + 16]; if(t1 < 0) t1 = 0;
  const int ksw = KSW32(lane);
  const u16* gA0 = Ah2 + (size_t)t0 * E_ + ksw;
  const u16* gA1 = Ah2 + (size_t)t1 * E_ + ksw;
  const u16* gB0 = Bt + (size_t)(tn + wid*32 + (lane >> 2)) * E_ + ksw;
  const u16* gB1 = gB0 + (size_t)16 * E_;
  u16* lA0 = As0 + wid*1024; u16* lA1 = lA0 + 512;
  u16* lB0 = Bs0 + wid*1024; u16* lB1 = lB0 + 512;
  u16* lA0b = As1 + wid*1024; u16* lA1b = lA0b + 512;
  u16* lB0b = Bs1 + wid*1024; u16* lB1b = lB0b + 512;
  const int fo = FRAGOFF(lane);
  const int fA = wm * 2048, fB = wn * 2048;

  const f32x4 zero = {0.f,0.f,0.f,0.f};
  f32x4 acc[4][4];
  #pragma unroll
  for(int m = 0; m < 4; m++)
    #pragma unroll
    for(int n = 0; n < 4; n++) acc[m][n] = zero;

  for(int k0 = 0; k0 < E_; k0 += 64){
    __syncthreads();
    gl_lds16(gA0 + k0, lA0);  gl_lds16(gA1 + k0, lA1);
    gl_lds16(gB0 + k0, lB0);  gl_lds16(gB1 + k0, lB1);
    gl_lds16(gA0 + k0+32, lA0b); gl_lds16(gA1 + k0+32, lA1b);
    gl_lds16(gB0 + k0+32, lB0b); gl_lds16(gB1 + k0+32, lB1b);
    __syncthreads();
    bf16x8 aF[4], bF[4];
    #pragma unroll
    for(int m = 0; m < 4; m++) aF[m] = *(const bf16x8*)(As0 + fA + m*512 + fo);
    #pragma unroll
    for(int n = 0; n < 4; n++) bF[n] = *(const bf16x8*)(Bs0 + fB + n*512 + fo);
    #pragma unroll
    for(int m = 0; m < 4; m++)
      #pragma unroll
      for(int n = 0; n < 4; n++)
        acc[m][n] = __builtin_amdgcn_mfma_f32_16x16x32_bf16(aF[m], bF[n], acc[m][n], 0, 0, 0);
    #pragma unroll
    for(int m = 0; m < 4; m++) aF[m] = *(const bf16x8*)(As1 + fA + m*512 + fo);
    #pragma unroll
    for(int n = 0; n < 4; n++) bF[n] = *(const bf16x8*)(Bs1 + fB + n*512 + fo);
    #pragma unroll
    for(int m = 0; m < 4; m++)
      #pragma unroll
      for(int n = 0; n < 4; n++)
        acc[m][n] = __builtin_amdgcn_mfma_f32_16x16x32_bf16(aF[m], bF[n], acc[m][n], 0, 0, 0);
  }
  #pragma unroll
  for(int m = 0; m < 4; m++){
    const int row = rowTile + wm*64 + m*16 + ((lane >> 4) << 2);
    #pragma unroll
    for(int n = 0; n < 4; n++){
      const int col = tn + wn*64 + n*16 + (lane & 15);
      const float bc = b9up[e * DFF_ + col];
      #pragma unroll
      for(int r = 0; r < 4; r++)
        ehid[(size_t)(row + r) * DFF_ + col] = f2bf(gelu_f(acc[m][n][r] + bc));
    }
  }
}

// ---- downmoe: BM=64 + chunk swizzle + COUNTED-VMCNT 2-buffer pipeline ----
// The one untested cell: loads in flight ACROSS the barrier (T4), no sched_barrier
// (m141: order-pinning was r5's confound). Stage(t+1) issued before compute(t);
// VMCNT(6) waits only tile-t's loads; t+1's ride through both barriers.
__launch_bounds__(256)
__global__ void downmoe_kernel(const u16* __restrict__ ehid, const u16* __restrict__ W2T,
                               const float* __restrict__ b9dn,
                               const int* __restrict__ rowlist, const float* __restrict__ rowgate,
                               const int* __restrict__ aoff, float* __restrict__ outF)
{
  const int nwg = (int)(gridDim.x * gridDim.y);          // 1664, divisible by 8
  const int b_lin = (int)(blockIdx.x + blockIdx.y * gridDim.x);
  const int b2 = (b_lin & 7) * (nwg >> 3) + (b_lin >> 3);
  const int bx = b2 & 7, by = b2 >> 3;                   // y-major decode (gridDim.x==8)
  const int rowTile = by * 64;
  if(rowTile >= aoff[9]) return;
  int e = 0;
  #pragma unroll
  for(int i = 1; i <= 8; i++) if(rowTile >= aoff[i]) e = i;
  // 2 buffers x full BK=64 tile: A 64x64 (8KB), B 128x64 (16KB) -> 48KB LDS
  __shared__ __align__(16) u16 As[2][4096], Bs[2][8192];
  const int tid = threadIdx.x, lane = tid & 63, wid = tid >> 6;
  const int wm = wid >> 1, wn = wid & 1;                 // wave tile 32x64
  const int tn = bx * 128;
  const u16* Bt = W2T + (size_t)e * E_ * DFF_;

  const int ksw = KSW32(lane);
  const u16* gA = ehid + (size_t)(rowTile + wid*16 + (lane >> 2)) * DFF_ + ksw;
  const u16* gB0 = Bt + (size_t)(tn + wid*32 + (lane >> 2)) * DFF_ + ksw;
  const u16* gB1 = gB0 + (size_t)16 * DFF_;
  const int segA = wid * 512, segB = wid * 1024;
  const int fo = FRAGOFF(lane);
  const int fA = wm * 1024, fB = wn * 2048;

  const f32x4 zero = {0.f,0.f,0.f,0.f};
  f32x4 acc[2][4];
  #pragma unroll
  for(int m = 0; m < 2; m++)
    #pragma unroll
    for(int n = 0; n < 4; n++) acc[m][n] = zero;

  auto stage = [&](int t, int cb){
    const int ko = t << 6;
    gl_lds16(gA + ko, &As[cb][segA]);                    // half0 rows
    gl_lds16(gB0 + ko, &Bs[cb][segB]); gl_lds16(gB1 + ko, &Bs[cb][segB + 512]);
    gl_lds16(gA + ko + 32, &As[cb][2048 + segA]);        // half1
    gl_lds16(gB0 + ko + 32, &Bs[cb][4096 + segB]); gl_lds16(gB1 + ko + 32, &Bs[cb][4096 + segB + 512]);
  };
  auto compute = [&](int cb){
    bf16x8 aF[2], bF[4];
    #pragma unroll
    for(int h = 0; h < 2; h++){
      const u16* as = &As[cb][h * 2048];
      const u16* bs = &Bs[cb][h * 4096];
      #pragma unroll
      for(int m = 0; m < 2; m++) aF[m] = *(const bf16x8*)(as + fA + m*512 + fo);
      #pragma unroll
      for(int n = 0; n < 4; n++) bF[n] = *(const bf16x8*)(bs + fB + n*512 + fo);
      #pragma unroll
      for(int m = 0; m < 2; m++)
        #pragma unroll
        for(int n = 0; n < 4; n++)
          acc[m][n] = __builtin_amdgcn_mfma_f32_16x16x32_bf16(aF[m], bF[n], acc[m][n], 0, 0, 0);
    }
  };

  const int nt = DFF_ >> 6;   // 64 K-steps
  stage(0, 0);
  for(int t = 0; t < nt - 1; ++t){
    stage(t + 1, (t + 1) & 1);
    VMCNT(6);                              // tile-t landed; t+1's 6 stay in flight
    __builtin_amdgcn_s_barrier();
    compute(t & 1);
    __builtin_amdgcn_s_barrier();          // all waves done reading buf before restage
  }
  VMCNT(0);
  __builtin_amdgcn_s_barrier();
  compute((nt - 1) & 1);

  #pragma unroll
  for(int m = 0; m < 2; m++){
    const int row = rowTile + wm*32 + m*16 + ((lane >> 4) << 2);
    #pragma unroll
    for(int r = 0; r < 4; r++){
      const int rr = row + r;
      const int tok = rowlist[rr];
      if(tok < 0) continue;
      const float g = rowgate[rr];
      #pragma unroll
      for(int n = 0; n < 4; n++){
        const int col = tn + wn*64 + n*16 + (lane & 15);
        atomicAdd(&outF[(size_t)tok * E_ + col], g * (acc[m][n][r] + b9dn[e * E_ + col]));
      }
    }
  }
}

extern "C" void kernel_launch(void* const* d_in, const int* in_sizes, int n_in,
                              void* d_out, int out_size, void* d_ws, size_t ws_size,
                              hipStream_t stream)
{
  (void)in_sizes; (void)n_in; (void)out_size;
  const float* x    = (const float*)d_in[0];
  const float* ln1g = (const float*)d_in[1];
  const float* ln1b = (const float*)d_in[2];
  const float* wq   = (const float*)d_in[3];
  const float* bq   = (const float*)d_in[4];
  const float* wk   = (const float*)d_in[5];
  const float* bk   = (const float*)d_in[6];
  const float* wv   = (const float*)d_in[7];
  const float* bv   = (const float*)d_in[8];
  const float* wo   = (const float*)d_in[9];
  const float* bo   = (const float*)d_in[10];
  const float* ln2g = (const float*)d_in[11];
  const float* ln2b = (const float*)d_in[12];
  const float* sw1  = (const float*)d_in[13];
  const float* sb1  = (const float*)d_in[14];
  const float* sw2  = (const float*)d_in[15];
  const float* sb2  = (const float*)d_in[16];
  const float* ew1  = (const float*)d_in[17];
  const float* eb1  = (const float*)d_in[18];
  const float* ew2  = (const float*)d_in[19];
  const float* eb2  = (const float*)d_in[20];
  const float* wgate= (const float*)d_in[21];
  float* out = (float*)d_out;
  char* ws = (char*)d_ws;
  const size_t MB = 1024ull * 1024ull;
  const bool big = (ws_size >= 194 * MB);

  // router/scalar block pointers (offset chosen per path)
  char* rt = big ? (ws + 192*MB) : (ws + 24*MB);
  float* probs   = (float*)(rt);
  float* tkgate  = (float*)(rt + 131072);
  int*   tkidx   = (int*)  (rt + 163840);
  int*   counts  = (int*)  (rt + 196608);
  int*   aoff    = (int*)  (rt + 196672);
  int*   rowlist = (int*)  (rt + 196800);
  float* rowgate = (float*)(rt + 250560);
  float* bcat    = (float*)(rt + 304320);
  float* b9up    = (float*)(rt + 316608);
  float* b9dn    = (float*)(rt + 464064);

  if(big){
    // ---- unified layout (needs 193MB) ----
    u16* h    = (u16*)(ws + 0);        // 8MB   (dead after qkv)
    u16* qkvb = (u16*)(ws + 8*MB);     // 24MB  (dead after attn)
    u16* ctx  = (u16*)(ws + 32*MB);    // 8MB   (dead after o-proj)
    u16* wT4  = (u16*)(ws + 40*MB);    // 8MB   (dead after o-proj)
    u16* ehid = (u16*)(ws + 0);        // 105MB (written by upmoe, over dead attn-phase bufs)
    u16* W1T  = (u16*)(ws + 112*MB);   // 72MB = 9 panels; later re-used as W2T
    u16* W2T  = W1T;
    u16* h2   = (u16*)(ws + 184*MB);   // 8MB

    prep_kernel<<<64, 256, 0, stream>>>(bq, bk, bv, bcat, counts, rowlist, eb1, sb1, b9up, eb2, sb2, b9dn);
    transpose4_kernel<<<dim3(16,16,4), 256, 0, stream>>>(wq, wk, wv, wo, wT4);
    transpose9_kernel<<<dim3(16,64,9), 256, 0, stream>>>(ew1, sw1, W1T, E_, DFF_);
    ln_kernel<<<NT_, 256, 0, stream>>>(x, ln1g, ln1b, h);
    gemm_kernel<0><<<dim3(24,32), 256, 0, stream>>>(h, wT4, QS_, E_, bcat, qkvb);
    attn_kernel<<<dim3(16,64), 256, 0, stream>>>(qkvb, ctx);
    gemm64_kernel<2><<<dim3(8,64), 256, 0, stream>>>(ctx, wT4 + 3u*1024*1024, E_, E_, bo, out, x);
    ln_router_kernel<<<NT_, 256, 0, stream>>>(out, ln2g, ln2b, h2, wgate, probs, tkgate, tkidx, counts);
    route_kernel<<<1, 256, 0, stream>>>(counts, tkidx, tkgate, probs, aoff, rowlist, rowgate,
                                        out + (size_t)NT_ * E_, 1);
    upmoe_kernel<<<dim3(32,104), 256, 0, stream>>>(h2, W1T, b9up, rowlist, aoff, ehid);
    transpose9_kernel<<<dim3(64,16,9), 256, 0, stream>>>(ew2, sw2, W2T, DFF_, E_);
    downmoe_kernel<<<dim3(8,208), 256, 0, stream>>>(ehid, W2T, b9dn, rowlist, rowgate, aoff, out);
  } else {
    // ---- legacy serial layout (<=168MB) ----
    u16* h    = (u16*)(ws + 0);
    u16* h2   = (u16*)(ws + 8*MB);
    u16* wT4  = (u16*)(ws + 16*MB);
    u16* swT  = wT4;
    u16* qkvb = (u16*)(ws + 32*MB);
    u16* ctx  = (u16*)(ws + 56*MB);
    u16* hidS = (u16*)(ws + 64*MB);
    u16* ewT  = (u16*)(ws + 32*MB);
    u16* ehid = (u16*)(ws + 96*MB);

    prep_kernel<<<64, 256, 0, stream>>>(bq, bk, bv, bcat, counts, rowlist, eb1, sb1, b9up, eb2, sb2, b9dn);
    transpose4_kernel<<<dim3(16,16,4), 256, 0, stream>>>(wq, wk, wv, wo, wT4);
    ln_kernel<<<NT_, 256, 0, stream>>>(x, ln1g, ln1b, h);
    gemm_kernel<0><<<dim3(24,32), 256, 0, stream>>>(h, wT4, QS_, E_, bcat, qkvb);
    attn_kernel<<<dim3(16,64), 256, 0, stream>>>(qkvb, ctx);
    gemm64_kernel<2><<<dim3(8,64), 256, 0, stream>>>(ctx, wT4 + 3u*1024*1024, E_, E_, bo, out, x);
    ln_router_kernel<<<NT_, 256, 0, stream>>>(out, ln2g, ln2b, h2, wgate, probs, tkgate, tkidx, counts);
    transpose_kernel<<<dim3(16,64), 256, 0, stream>>>(sw1, swT, E_, DFF_);
    gemm_kernel<1><<<dim3(32,32), 256, 0, stream>>>(h2, swT, DFF_, E_, sb1, hidS);
    transpose_kernel<<<dim3(64,16), 256, 0, stream>>>(sw2, swT, DFF_, E_);
    gemm64_kernel<3><<<dim3(8,64), 256, 0, stream>>>(hidS, swT, E_, DFF_, sb2, out, nullptr);
    route_kernel<<<1, 256, 0, stream>>>(counts, tkidx, tkgate, probs, aoff, rowlist, rowgate,
                                        out + (size_t)NT_ * E_, 0);
    transpose9_kernel<<<dim3(16,64,8), 256, 0, stream>>>(ew1, sw1, ewT, E_, DFF_);
    upmoe_kernel<<<dim3(32,104), 256, 0, stream>>>(h2, ewT, b9up, rowlist, aoff, ehid);
    transpose9_kernel<<<dim3(64,16,8), 256, 0, stream>>>(ew2, sw2, ewT, DFF_, E_);
    downmoe_kernel<<<dim3(8,208), 256, 0, stream>>>(ehid, ewT, b9dn, rowlist, rowgate, aoff, out);
  }
}

// Round 12
// 763.428 us; speedup vs baseline: 1.0570x; 1.0570x over previous
//
#include <hip/hip_runtime.h>
#include <stdint.h>

#define B_    4
#define S_    1024
#define E_    1024
#define H_    16
#define NE_   8
#define DFF_  4096
#define NT_   4096          // B_*S_ tokens
#define QS_   3072          // fused qkv row stride
#define ROWCAP9_ 13440      // 8 experts padded (<=9216) + 4096 shared + slack

typedef unsigned short u16;
typedef short bf16x8 __attribute__((ext_vector_type(8)));
typedef float f32x4 __attribute__((ext_vector_type(4)));

__device__ __forceinline__ float bf2f(u16 u){ unsigned v = ((unsigned)u) << 16; return __builtin_bit_cast(float, v); }
__device__ __forceinline__ u16 f2bf(float f){ unsigned x = __builtin_bit_cast(unsigned, f); return (u16)((x + 0x7FFFu + ((x >> 16) & 1u)) >> 16); }
__device__ __forceinline__ float gelu_f(float x){ return 0.5f * x * (1.f + erff(x * 0.70710678118f)); }

// async global->LDS, 16B per lane; LDS dest = wave-uniform base + lane*16
__device__ __forceinline__ void gl_lds16(const u16* g, u16* l){
  __builtin_amdgcn_global_load_lds((__attribute__((address_space(1))) void*)(const_cast<u16*>(g)),
                                   (__attribute__((address_space(3))) void*)(l), 16, 0, 0);
}

// LDS XOR swizzle (32-u16 rows, 4 slots of 16B) — conflict-free, verified r4 (13.2M -> 0).
#define KSW32(l)   ((((l) & 3) ^ (((l) >> 3) & 3)) << 3)
#define FRAGOFF(l) (((l) & 15) * 32 + (((((l) >> 4) ^ (((l) >> 1) & 3))) << 3))

// ---------------- LayerNorm: f32 in -> bf16 out ----------------
__launch_bounds__(256)
__global__ void ln_kernel(const float* __restrict__ x, const float* __restrict__ g,
                          const float* __restrict__ be, u16* __restrict__ out)
{
  const int row = blockIdx.x;
  const float4 v = ((const float4*)(x + (size_t)row * E_))[threadIdx.x];
  float s = v.x + v.y + v.z + v.w;
  #pragma unroll
  for(int mm = 32; mm >= 1; mm >>= 1) s += __shfl_xor(s, mm);
  __shared__ float red[8];
  const int wid = threadIdx.x >> 6;
  if((threadIdx.x & 63) == 0) red[wid] = s;
  __syncthreads();
  const float mean = (red[0] + red[1] + red[2] + red[3]) * (1.0f / E_);
  const float d0 = v.x - mean, d1 = v.y - mean, d2 = v.z - mean, d3 = v.w - mean;
  float q2 = d0*d0 + d1*d1 + d2*d2 + d3*d3;
  #pragma unroll
  for(int mm = 32; mm >= 1; mm >>= 1) q2 += __shfl_xor(q2, mm);
  if((threadIdx.x & 63) == 0) red[4 + wid] = q2;
  __syncthreads();
  const float var = (red[4] + red[5] + red[6] + red[7]) * (1.0f / E_);
  const float rs = rsqrtf(var + 1e-5f);
  const float4 gg = ((const float4*)g)[threadIdx.x];
  const float4 bb = ((const float4*)be)[threadIdx.x];
  ushort4 o;
  o.x = f2bf(d0 * rs * gg.x + bb.x);
  o.y = f2bf(d1 * rs * gg.y + bb.y);
  o.z = f2bf(d2 * rs * gg.z + bb.z);
  o.w = f2bf(d3 * rs * gg.w + bb.w);
  ((ushort4*)(out + (size_t)row * E_))[threadIdx.x] = o;
}

// ---------------- fused LayerNorm2 + router (one block per token) ----------------
__launch_bounds__(256)
__global__ void ln_router_kernel(const float* __restrict__ x, const float* __restrict__ g,
                                 const float* __restrict__ be, u16* __restrict__ out,
                                 const float* __restrict__ wg,
                                 float* __restrict__ probs, float* __restrict__ tkgate,
                                 int* __restrict__ tkidx, int* __restrict__ counts)
{
  const int row = blockIdx.x;
  const int tid = threadIdx.x, lane = tid & 63, wid = tid >> 6;
  const float4 v = ((const float4*)(x + (size_t)row * E_))[tid];
  float s = v.x + v.y + v.z + v.w;
  #pragma unroll
  for(int mm = 32; mm >= 1; mm >>= 1) s += __shfl_xor(s, mm);
  __shared__ float red[8];
  __shared__ float part[4][8];
  if(lane == 0) red[wid] = s;
  __syncthreads();
  const float mean = (red[0] + red[1] + red[2] + red[3]) * (1.0f / E_);
  const float d0 = v.x - mean, d1 = v.y - mean, d2 = v.z - mean, d3 = v.w - mean;
  float q2 = d0*d0 + d1*d1 + d2*d2 + d3*d3;
  #pragma unroll
  for(int mm = 32; mm >= 1; mm >>= 1) q2 += __shfl_xor(q2, mm);
  if(lane == 0) red[4 + wid] = q2;
  __syncthreads();
  const float var = (red[4] + red[5] + red[6] + red[7]) * (1.0f / E_);
  const float rs = rsqrtf(var + 1e-5f);
  const float4 gg = ((const float4*)g)[tid];
  const float4 bb = ((const float4*)be)[tid];
  ushort4 o;
  o.x = f2bf(d0 * rs * gg.x + bb.x);
  o.y = f2bf(d1 * rs * gg.y + bb.y);
  o.z = f2bf(d2 * rs * gg.z + bb.z);
  o.w = f2bf(d3 * rs * gg.w + bb.w);
  ((ushort4*)(out + (size_t)row * E_))[tid] = o;
  // router partials on bf16-rounded h2 (bit-identical to reading h2 back)
  const float h0 = bf2f(o.x), h1 = bf2f(o.y), h2v = bf2f(o.z), h3 = bf2f(o.w);
  float a[8];
  #pragma unroll
  for(int e = 0; e < 8; e++) a[e] = 0.f;
  const float* wr = wg + (size_t)(tid * 4) * NE_;
  #pragma unroll
  for(int j = 0; j < 4; j++){
    const float hj = (j == 0) ? h0 : (j == 1) ? h1 : (j == 2) ? h2v : h3;
    const float4 w0 = *(const float4*)(wr + j * NE_);
    const float4 w1 = *(const float4*)(wr + j * NE_ + 4);
    a[0] += hj * w0.x; a[1] += hj * w0.y; a[2] += hj * w0.z; a[3] += hj * w0.w;
    a[4] += hj * w1.x; a[5] += hj * w1.y; a[6] += hj * w1.z; a[7] += hj * w1.w;
  }
  #pragma unroll
  for(int mm = 1; mm < 64; mm <<= 1)
    #pragma unroll
    for(int e = 0; e < 8; e++) a[e] += __shfl_xor(a[e], mm);
  if(lane == 0)
    #pragma unroll
    for(int e = 0; e < 8; e++) part[wid][e] = a[e];
  __syncthreads();
  if(tid == 0){
    float lg[8];
    #pragma unroll
    for(int e = 0; e < 8; e++) lg[e] = part[0][e] + part[1][e] + part[2][e] + part[3][e];
    float mx = lg[0];
    #pragma unroll
    for(int e = 1; e < 8; e++) mx = fmaxf(mx, lg[e]);
    float se = 0.f, ex[8];
    #pragma unroll
    for(int e = 0; e < 8; e++){ ex[e] = expf(lg[e] - mx); se += ex[e]; }
    const float inv = 1.f / se;
    float* pr = probs + (size_t)row * 8;
    #pragma unroll
    for(int e = 0; e < 8; e++) pr[e] = ex[e] * inv;
    int i1 = 0; float v1 = lg[0];
    #pragma unroll
    for(int e = 1; e < 8; e++) if(lg[e] > v1){ v1 = lg[e]; i1 = e; }
    int i2 = -1; float v2 = -3.4e38f;
    #pragma unroll
    for(int e = 0; e < 8; e++) if(e != i1 && lg[e] > v2){ v2 = lg[e]; i2 = e; }
    const float t = expf(v2 - v1);
    tkidx[row*2] = i1; tkidx[row*2+1] = i2;
    tkgate[row*2] = 1.f / (1.f + t); tkgate[row*2+1] = t / (1.f + t);
    atomicAdd(&counts[i1], 1); atomicAdd(&counts[i2], 1);
  }
}

// ------------- transpose core: W (KxN f32) -> WT (NxK bf16) -------------
__device__ __forceinline__ void transpose_body(const float* __restrict__ W, u16* __restrict__ WT, int K, int N)
{
  __shared__ __align__(16) u16 t[64][72];
  const int k0 = blockIdx.x * 64, n0 = blockIdx.y * 64;
  const int tid = threadIdx.x;
  const int kr = tid >> 2;
  const int nc = (tid & 3) * 4;
  #pragma unroll
  for(int p = 0; p < 4; p++){
    float4 v = *(const float4*)(W + (size_t)(k0 + kr) * N + n0 + nc + p * 16);
    t[nc + p*16 + 0][kr] = f2bf(v.x);
    t[nc + p*16 + 1][kr] = f2bf(v.y);
    t[nc + p*16 + 2][kr] = f2bf(v.z);
    t[nc + p*16 + 3][kr] = f2bf(v.w);
  }
  __syncthreads();
  const int nr = tid >> 3;
  const int kg = (tid & 7) * 8;
  #pragma unroll
  for(int p = 0; p < 2; p++){
    const int nn = nr + p * 32;
    unsigned u0 = t[nn][kg+0], u1 = t[nn][kg+1], u2 = t[nn][kg+2], u3 = t[nn][kg+3];
    unsigned u4 = t[nn][kg+4], u5 = t[nn][kg+5], u6 = t[nn][kg+6], u7 = t[nn][kg+7];
    uint4 o;
    o.x = u0 | (u1 << 16); o.y = u2 | (u3 << 16); o.z = u4 | (u5 << 16); o.w = u6 | (u7 << 16);
    *(uint4*)(WT + (size_t)(n0 + nn) * K + k0 + kg) = o;
  }
}

__launch_bounds__(256)
__global__ void transpose_kernel(const float* __restrict__ W, u16* __restrict__ WT, int K, int N)
{ transpose_body(W, WT, K, N); }

// 4 attention weights (1024x1024 each) in one launch, z selects
__launch_bounds__(256)
__global__ void transpose4_kernel(const float* wq, const float* wk, const float* wv, const float* wo,
                                  u16* __restrict__ WT)
{
  const float* W = (blockIdx.z == 0) ? wq : (blockIdx.z == 1) ? wk : (blockIdx.z == 2) ? wv : wo;
  transpose_body(W, WT + (size_t)blockIdx.z * E_ * E_, E_, E_);
}

// 9-panel transpose: z<8 -> ew + z*K*N ; z==8 -> sw (shared as expert 8)
__launch_bounds__(256)
__global__ void transpose9_kernel(const float* __restrict__ ew, const float* __restrict__ sw,
                                  u16* __restrict__ WT, int K, int N)
{
  const float* W = (blockIdx.z < 8) ? (ew + (size_t)blockIdx.z * K * N) : sw;
  transpose_body(W, WT + (size_t)blockIdx.z * K * N, K, N);
}

// ---------------- prep: bcat, router init, 9-expert bias tables ----------------
__global__ void prep_kernel(const float* __restrict__ bq, const float* __restrict__ bk,
                            const float* __restrict__ bv, float* __restrict__ bcat,
                            int* __restrict__ counts, int* __restrict__ rowlist,
                            const float* __restrict__ eb1, const float* __restrict__ sb1,
                            float* __restrict__ b9up,
                            const float* __restrict__ eb2, const float* __restrict__ sb2,
                            float* __restrict__ b9dn)
{
  const int stride = gridDim.x * 256;
  for(int i = blockIdx.x * 256 + threadIdx.x; i < 9 * DFF_; i += stride){
    b9up[i] = (i < 8 * DFF_) ? eb1[i] : sb1[i - 8 * DFF_];
    if(i < 9 * E_)   b9dn[i] = (i < 8 * E_) ? eb2[i] : sb2[i - 8 * E_];
    if(i < QS_)      bcat[i] = (i < E_) ? bq[i] : (i < 2*E_) ? bk[i - E_] : bv[i - 2*E_];
    if(i < 16)       counts[i] = 0;
    if(i < ROWCAP9_) rowlist[i] = -1;
  }
}

// ---------------- route: scan + build + aux in ONE single-block kernel ----------------
__launch_bounds__(256)
__global__ void route_kernel(const int* __restrict__ counts, const int* __restrict__ tkidx,
                             const float* __restrict__ tkgate, const float* __restrict__ probs,
                             int* __restrict__ aoff, int* __restrict__ rowlist,
                             float* __restrict__ rowgate, float* __restrict__ outaux, int addShared)
{
  __shared__ int cur[8];
  __shared__ int aoffs[10];
  __shared__ float part[4][8];
  const int tid = threadIdx.x, lane = tid & 63, wid = tid >> 6;
  if(tid == 0){
    int o = 0;
    for(int e = 0; e < 8; e++){ aoffs[e] = o; cur[e] = o; o += ((counts[e] + 127) >> 7) << 7; }
    aoffs[8] = o; aoffs[9] = o + (addShared ? NT_ : 0);
    for(int e = 0; e < 10; e++) aoff[e] = aoffs[e];
  }
  __syncthreads();
  for(int t = tid; t < NT_; t += 256){
    #pragma unroll
    for(int kk = 0; kk < 2; kk++){
      const int e = tkidx[t*2 + kk];
      const int pos = atomicAdd(&cur[e], 1);
      rowlist[pos] = t; rowgate[pos] = tkgate[t*2 + kk];
    }
    if(addShared){ rowlist[aoffs[8] + t] = t; rowgate[aoffs[8] + t] = 1.f; }
  }
  // aux loss
  float a[8];
  #pragma unroll
  for(int e = 0; e < 8; e++) a[e] = 0.f;
  for(int t = tid; t < NT_; t += 256){
    const float* p = probs + (size_t)t * 8;
    #pragma unroll
    for(int e = 0; e < 8; e++) a[e] += p[e];
  }
  #pragma unroll
  for(int mm = 1; mm < 64; mm <<= 1)
    #pragma unroll
    for(int e = 0; e < 8; e++) a[e] += __shfl_xor(a[e], mm);
  if(lane == 0)
    #pragma unroll
    for(int e = 0; e < 8; e++) part[wid][e] = a[e];
  __syncthreads();
  if(tid == 0){
    float aux = 0.f;
    for(int e = 0; e < 8; e++){
      const float P = (part[0][e] + part[1][e] + part[2][e] + part[3][e]) / (float)NT_;
      const float f = (float)counts[e] / (float)NT_;
      aux += P * f;
    }
    outaux[0] = (float)NE_ * aux;
  }
}

// ======== GEMM BM=128, BN=128, BK=64 (r3 structure + swizzle) ========
// MODE 0: outB = bf16(acc+bias)        (fused qkv)
// MODE 1: outB = bf16(gelu(acc+bias))  (legacy shared FFN up)
template<int MODE>
__launch_bounds__(256)
__global__ void gemm_kernel(const u16* __restrict__ A, const u16* __restrict__ Bt,
                            int N, int Kd, const float* __restrict__ bias,
                            u16* __restrict__ outB)
{
  __shared__ __align__(16) u16 As0[4096], Bs0[4096], As1[4096], Bs1[4096];
  const int tid = threadIdx.x, lane = tid & 63, wid = tid >> 6;
  const int wm = wid >> 1, wn = wid & 1;
  const int tm = blockIdx.y * 128, tn = blockIdx.x * 128;

  const f32x4 zero = {0.f, 0.f, 0.f, 0.f};
  f32x4 acc[4][4];
  #pragma unroll
  for(int m = 0; m < 4; m++)
    #pragma unroll
    for(int n = 0; n < 4; n++) acc[m][n] = zero;

  const int ksw = KSW32(lane);
  const u16* gA0 = A  + (size_t)(tm + wid*32 + (lane >> 2)) * Kd + ksw;
  const u16* gA1 = gA0 + (size_t)16 * Kd;
  const u16* gB0 = Bt + (size_t)(tn + wid*32 + (lane >> 2)) * Kd + ksw;
  const u16* gB1 = gB0 + (size_t)16 * Kd;
  u16* lA0 = As0 + wid*1024; u16* lA1 = lA0 + 512;
  u16* lB0 = Bs0 + wid*1024; u16* lB1 = lB0 + 512;
  u16* lA0b = As1 + wid*1024; u16* lA1b = lA0b + 512;
  u16* lB0b = Bs1 + wid*1024; u16* lB1b = lB0b + 512;
  const int fo = FRAGOFF(lane);
  const int fA = wm * 2048, fB = wn * 2048;

  for(int k0 = 0; k0 < Kd; k0 += 64){
    __syncthreads();
    gl_lds16(gA0 + k0, lA0);  gl_lds16(gA1 + k0, lA1);
    gl_lds16(gB0 + k0, lB0);  gl_lds16(gB1 + k0, lB1);
    gl_lds16(gA0 + k0+32, lA0b); gl_lds16(gA1 + k0+32, lA1b);
    gl_lds16(gB0 + k0+32, lB0b); gl_lds16(gB1 + k0+32, lB1b);
    __syncthreads();
    bf16x8 aF[4], bF[4];
    #pragma unroll
    for(int m = 0; m < 4; m++) aF[m] = *(const bf16x8*)(As0 + fA + m*512 + fo);
    #pragma unroll
    for(int n = 0; n < 4; n++) bF[n] = *(const bf16x8*)(Bs0 + fB + n*512 + fo);
    #pragma unroll
    for(int m = 0; m < 4; m++)
      #pragma unroll
      for(int n = 0; n < 4; n++)
        acc[m][n] = __builtin_amdgcn_mfma_f32_16x16x32_bf16(aF[m], bF[n], acc[m][n], 0, 0, 0);
    #pragma unroll
    for(int m = 0; m < 4; m++) aF[m] = *(const bf16x8*)(As1 + fA + m*512 + fo);
    #pragma unroll
    for(int n = 0; n < 4; n++) bF[n] = *(const bf16x8*)(Bs1 + fB + n*512 + fo);
    #pragma unroll
    for(int m = 0; m < 4; m++)
      #pragma unroll
      for(int n = 0; n < 4; n++)
        acc[m][n] = __builtin_amdgcn_mfma_f32_16x16x32_bf16(aF[m], bF[n], acc[m][n], 0, 0, 0);
  }

  #pragma unroll
  for(int m = 0; m < 4; m++){
    const int row = tm + wm*64 + m*16 + ((lane >> 4) << 2);
    #pragma unroll
    for(int n = 0; n < 4; n++){
      const int col = tn + wn*64 + n*16 + (lane & 15);
      const float bc = bias[col];
      #pragma unroll
      for(int r = 0; r < 4; r++){
        const float v = acc[m][n][r] + bc;
        const size_t idx = (size_t)(row + r) * N + col;
        if constexpr(MODE == 0) outB[idx] = f2bf(v);
        else outB[idx] = f2bf(gelu_f(v));
      }
    }
  }
}

// ======== GEMM BM=64, BN=128, BK=64 (o-proj / legacy FFN-down) ========
// MODE 2: outF = resid + acc + bias
// MODE 3: outF += acc + bias
template<int MODE>
__launch_bounds__(256)
__global__ void gemm64_kernel(const u16* __restrict__ A, const u16* __restrict__ Bt,
                              int N, int Kd, const float* __restrict__ bias,
                              float* __restrict__ outF, const float* __restrict__ resid)
{
  __shared__ __align__(16) u16 As0[2048], As1[2048], Bs0[4096], Bs1[4096];
  const int tid = threadIdx.x, lane = tid & 63, wid = tid >> 6;
  const int wm = wid >> 1, wn = wid & 1;
  const int tm = blockIdx.y * 64, tn = blockIdx.x * 128;

  const f32x4 zero = {0.f, 0.f, 0.f, 0.f};
  f32x4 acc[2][4];
  #pragma unroll
  for(int m = 0; m < 2; m++)
    #pragma unroll
    for(int n = 0; n < 4; n++) acc[m][n] = zero;

  const int ksw = KSW32(lane);
  const u16* gA = A + (size_t)(tm + wid*16 + (lane >> 2)) * Kd + ksw;
  const u16* gB0 = Bt + (size_t)(tn + wid*32 + (lane >> 2)) * Kd + ksw;
  const u16* gB1 = gB0 + (size_t)16 * Kd;
  u16* lA  = As0 + wid*512;  u16* lAb = As1 + wid*512;
  u16* lB0 = Bs0 + wid*1024; u16* lB1 = lB0 + 512;
  u16* lB0b = Bs1 + wid*1024; u16* lB1b = lB0b + 512;
  const int fo = FRAGOFF(lane);
  const int fA = wm * 1024, fB = wn * 2048;

  for(int k0 = 0; k0 < Kd; k0 += 64){
    __syncthreads();
    gl_lds16(gA + k0, lA);
    gl_lds16(gB0 + k0, lB0); gl_lds16(gB1 + k0, lB1);
    gl_lds16(gA + k0+32, lAb);
    gl_lds16(gB0 + k0+32, lB0b); gl_lds16(gB1 + k0+32, lB1b);
    __syncthreads();
    bf16x8 aF[2], bF[4];
    #pragma unroll
    for(int m = 0; m < 2; m++) aF[m] = *(const bf16x8*)(As0 + fA + m*512 + fo);
    #pragma unroll
    for(int n = 0; n < 4; n++) bF[n] = *(const bf16x8*)(Bs0 + fB + n*512 + fo);
    #pragma unroll
    for(int m = 0; m < 2; m++)
      #pragma unroll
      for(int n = 0; n < 4; n++)
        acc[m][n] = __builtin_amdgcn_mfma_f32_16x16x32_bf16(aF[m], bF[n], acc[m][n], 0, 0, 0);
    #pragma unroll
    for(int m = 0; m < 2; m++) aF[m] = *(const bf16x8*)(As1 + fA + m*512 + fo);
    #pragma unroll
    for(int n = 0; n < 4; n++) bF[n] = *(const bf16x8*)(Bs1 + fB + n*512 + fo);
    #pragma unroll
    for(int m = 0; m < 2; m++)
      #pragma unroll
      for(int n = 0; n < 4; n++)
        acc[m][n] = __builtin_amdgcn_mfma_f32_16x16x32_bf16(aF[m], bF[n], acc[m][n], 0, 0, 0);
  }

  #pragma unroll
  for(int m = 0; m < 2; m++){
    const int row = tm + wm*32 + m*16 + ((lane >> 4) << 2);
    #pragma unroll
    for(int n = 0; n < 4; n++){
      const int col = tn + wn*64 + n*16 + (lane & 15);
      const float bc = bias[col];
      #pragma unroll
      for(int r = 0; r < 4; r++){
        const float v = acc[m][n][r] + bc;
        const size_t idx = (size_t)(row + r) * N + col;
        if constexpr(MODE == 2) outF[idx] = resid[idx] + v;
        else outF[idx] += v;
      }
    }
  }
}

// ---------------- flash attention over fused qkv buffer [tok][3072] ----------------
__launch_bounds__(256)
__global__ void attn_kernel(const u16* __restrict__ qkv, u16* __restrict__ ctx)
{
  __shared__ __align__(16) u16 Ks[64 * 64];
  __shared__ __align__(16) u16 Vt[64 * 72];
  __shared__ __align__(16) u16 Ps[64 * 72];
  const int tid = threadIdx.x, lane = tid & 63, wid = tid >> 6;
  const int bh = blockIdx.y, bb = bh >> 4, hh = bh & 15;
  const int q0 = blockIdx.x * 64;
  const size_t tok0 = (size_t)bb * S_;
  const int hcol = hh * 64;

  bf16x8 aQ0, aQ1;
  {
    const u16* qp = qkv + (tok0 + q0 + wid*16 + (lane & 15)) * QS_ + hcol + ((lane >> 4) << 3);
    aQ0 = *(const bf16x8*)qp;
    aQ1 = *(const bf16x8*)(qp + 32);
  }
  const f32x4 zero = {0.f, 0.f, 0.f, 0.f};
  f32x4 accO[4]; float mrow[4], lrow[4];
  #pragma unroll
  for(int n = 0; n < 4; n++) accO[n] = zero;
  #pragma unroll
  for(int r = 0; r < 4; r++){ mrow[r] = -1e30f; lrow[r] = 0.f; }
  const float sc = 0.125f * 1.44269504f;
  const int ksw8 = (((lane & 7) ^ ((lane >> 3) & 7)) << 3);

  for(int kv0 = 0; kv0 < S_; kv0 += 64){
    __syncthreads();
    {
      const u16* gp = qkv + (tok0 + kv0 + wid*16 + (lane >> 3)) * QS_ + 1024 + hcol + ksw8;
      gl_lds16(gp, Ks + (wid*16) * 64);
      gl_lds16(gp + (size_t)8 * QS_, Ks + (wid*16 + 8) * 64);
    }
    {
      #pragma unroll
      for(int i = 0; i < 2; i++){
        const int tok = (tid >> 3) + i * 32;
        const int d0 = (tid & 7) << 3;
        bf16x8 vv = *(const bf16x8*)(qkv + (tok0 + kv0 + tok) * QS_ + 2048 + hcol + d0);
        #pragma unroll
        for(int j = 0; j < 8; j++) Vt[(d0 + j) * 72 + tok] = (u16)vv[j];
      }
    }
    __syncthreads();
    f32x4 sf[4];
    #pragma unroll
    for(int n = 0; n < 4; n++){
      const int rb = n*16 + (lane & 15);
      bf16x8 b0 = *(const bf16x8*)(Ks + rb*64 + ((((lane >> 4)    ) ^ (lane & 7)) << 3));
      bf16x8 b1 = *(const bf16x8*)(Ks + rb*64 + ((((lane >> 4) + 4) ^ (lane & 7)) << 3));
      f32x4 t = zero;
      t = __builtin_amdgcn_mfma_f32_16x16x32_bf16(aQ0, b0, t, 0, 0, 0);
      t = __builtin_amdgcn_mfma_f32_16x16x32_bf16(aQ1, b1, t, 0, 0, 0);
      sf[n] = t;
    }
    #pragma unroll
    for(int r = 0; r < 4; r++){
      const float s0 = sf[0][r]*sc, s1 = sf[1][r]*sc, s2 = sf[2][r]*sc, s3 = sf[3][r]*sc;
      float mx = fmaxf(fmaxf(s0, s1), fmaxf(s2, s3));
      #pragma unroll
      for(int mm = 1; mm < 16; mm <<= 1) mx = fmaxf(mx, __shfl_xor(mx, mm));
      const float mnew = fmaxf(mrow[r], mx);
      const float resc = exp2f(mrow[r] - mnew);
      mrow[r] = mnew;
      const float p0 = exp2f(s0 - mnew), p1 = exp2f(s1 - mnew);
      const float p2 = exp2f(s2 - mnew), p3 = exp2f(s3 - mnew);
      float ps = p0 + p1 + p2 + p3;
      #pragma unroll
      for(int mm = 1; mm < 16; mm <<= 1) ps += __shfl_xor(ps, mm);
      lrow[r] = lrow[r] * resc + ps;
      #pragma unroll
      for(int n = 0; n < 4; n++) accO[n][r] *= resc;
      const int prow = wid*16 + ((lane >> 4) << 2) + r;
      Ps[prow*72 +      (lane & 15)] = f2bf(p0);
      Ps[prow*72 + 16 + (lane & 15)] = f2bf(p1);
      Ps[prow*72 + 32 + (lane & 15)] = f2bf(p2);
      Ps[prow*72 + 48 + (lane & 15)] = f2bf(p3);
    }
    bf16x8 pa0 = *(const bf16x8*)(Ps + (wid*16 + (lane & 15)) * 72 + ((lane >> 4) << 3));
    bf16x8 pa1 = *(const bf16x8*)(Ps + (wid*16 + (lane & 15)) * 72 + 32 + ((lane >> 4) << 3));
    #pragma unroll
    for(int n = 0; n < 4; n++){
      bf16x8 b0 = *(const bf16x8*)(Vt + (n*16 + (lane & 15)) * 72 + ((lane >> 4) << 3));
      bf16x8 b1 = *(const bf16x8*)(Vt + (n*16 + (lane & 15)) * 72 + 32 + ((lane >> 4) << 3));
      accO[n] = __builtin_amdgcn_mfma_f32_16x16x32_bf16(pa0, b0, accO[n], 0, 0, 0);
      accO[n] = __builtin_amdgcn_mfma_f32_16x16x32_bf16(pa1, b1, accO[n], 0, 0, 0);
    }
  }
  const size_t cbase = tok0 * E_ + hcol;
  #pragma unroll
  for(int n = 0; n < 4; n++)
    #pragma unroll
    for(int r = 0; r < 4; r++){
      const int row = q0 + wid*16 + ((lane >> 4) << 2) + r;
      const int col = n*16 + (lane & 15);
      ctx[cbase + (size_t)row * E_ + col] = f2bf(accO[n][r] / lrow[r]);
    }
}

// ---- upmoe: gathered rows -> gelu hidden; 9 experts (8 routed + shared) ----
__launch_bounds__(256)
__global__ void upmoe_kernel(const u16* __restrict__ Ah2, const u16* __restrict__ W1T,
                             const float* __restrict__ b9up,
                             const int* __restrict__ rowlist, const int* __restrict__ aoff,
                             u16* __restrict__ ehid)
{
  const int rowTile = blockIdx.y * 128;
  if(rowTile >= aoff[9]) return;
  int e = 0;
  #pragma unroll
  for(int i = 1; i <= 8; i++) if(rowTile >= aoff[i]) e = i;
  __shared__ __align__(16) u16 As0[4096], Bs0[4096], As1[4096], Bs1[4096];
  const int tid = threadIdx.x, lane = tid & 63, wid = tid >> 6;
  const int wm = wid >> 1, wn = wid & 1;
  const int tn = blockIdx.x * 128;
  const u16* Bt = W1T + (size_t)e * DFF_ * E_;

  const int r0 = rowTile + wid*32 + (lane >> 2);
  int t0 = rowlist[r0];      if(t0 < 0) t0 = 0;
  int t1 = rowlist[r0 + 16]; if(t1 < 0) t1 = 0;
  const int ksw = KSW32(lane);
  const u16* gA0 = Ah2 + (size_t)t0 * E_ + ksw;
  const u16* gA1 = Ah2 + (size_t)t1 * E_ + ksw;
  const u16* gB0 = Bt + (size_t)(tn + wid*32 + (lane >> 2)) * E_ + ksw;
  const u16* gB1 = gB0 + (size_t)16 * E_;
  u16* lA0 = As0 + wid*1024; u16* lA1 = lA0 + 512;
  u16* lB0 = Bs0 + wid*1024; u16* lB1 = lB0 + 512;
  u16* lA0b = As1 + wid*1024; u16* lA1b = lA0b + 512;
  u16* lB0b = Bs1 + wid*1024; u16* lB1b = lB0b + 512;
  const int fo = FRAGOFF(lane);
  const int fA = wm * 2048, fB = wn * 2048;

  const f32x4 zero = {0.f,0.f,0.f,0.f};
  f32x4 acc[4][4];
  #pragma unroll
  for(int m = 0; m < 4; m++)
    #pragma unroll
    for(int n = 0; n < 4; n++) acc[m][n] = zero;

  for(int k0 = 0; k0 < E_; k0 += 64){
    __syncthreads();
    gl_lds16(gA0 + k0, lA0);  gl_lds16(gA1 + k0, lA1);
    gl_lds16(gB0 + k0, lB0);  gl_lds16(gB1 + k0, lB1);
    gl_lds16(gA0 + k0+32, lA0b); gl_lds16(gA1 + k0+32, lA1b);
    gl_lds16(gB0 + k0+32, lB0b); gl_lds16(gB1 + k0+32, lB1b);
    __syncthreads();
    bf16x8 aF[4], bF[4];
    #pragma unroll
    for(int m = 0; m < 4; m++) aF[m] = *(const bf16x8*)(As0 + fA + m*512 + fo);
    #pragma unroll
    for(int n = 0; n < 4; n++) bF[n] = *(const bf16x8*)(Bs0 + fB + n*512 + fo);
    #pragma unroll
    for(int m = 0; m < 4; m++)
      #pragma unroll
      for(int n = 0; n < 4; n++)
        acc[m][n] = __builtin_amdgcn_mfma_f32_16x16x32_bf16(aF[m], bF[n], acc[m][n], 0, 0, 0);
    #pragma unroll
    for(int m = 0; m < 4; m++) aF[m] = *(const bf16x8*)(As1 + fA + m*512 + fo);
    #pragma unroll
    for(int n = 0; n < 4; n++) bF[n] = *(const bf16x8*)(Bs1 + fB + n*512 + fo);
    #pragma unroll
    for(int m = 0; m < 4; m++)
      #pragma unroll
      for(int n = 0; n < 4; n++)
        acc[m][n] = __builtin_amdgcn_mfma_f32_16x16x32_bf16(aF[m], bF[n], acc[m][n], 0, 0, 0);
  }
  #pragma unroll
  for(int m = 0; m < 4; m++){
    const int row = rowTile + wm*64 + m*16 + ((lane >> 4) << 2);
    #pragma unroll
    for(int n = 0; n < 4; n++){
      const int col = tn + wn*64 + n*16 + (lane & 15);
      const float bc = b9up[e * DFF_ + col];
      #pragma unroll
      for(int r = 0; r < 4; r++)
        ehid[(size_t)(row + r) * DFF_ + col] = f2bf(gelu_f(acc[m][n][r] + bc));
    }
  }
}

// ---- downmoe: BM=64 + XCD chunk swizzle (r8/r10 best-measured config, exact) ----
__launch_bounds__(256)
__global__ void downmoe_kernel(const u16* __restrict__ ehid, const u16* __restrict__ W2T,
                               const float* __restrict__ b9dn,
                               const int* __restrict__ rowlist, const float* __restrict__ rowgate,
                               const int* __restrict__ aoff, float* __restrict__ outF)
{
  // chunk swizzle: HW XCD = linear_id % 8. Each XCD owns a contiguous y-chunk so
  // each ehid row-tile is read by ONE XCD (r8: FETCH 472->240MB).
  const int nwg = (int)(gridDim.x * gridDim.y);          // 1664, divisible by 8
  const int b_lin = (int)(blockIdx.x + blockIdx.y * gridDim.x);
  const int b2 = (b_lin & 7) * (nwg >> 3) + (b_lin >> 3);
  const int bx = b2 & 7, by = b2 >> 3;                   // y-major decode (gridDim.x==8)
  const int rowTile = by * 64;
  if(rowTile >= aoff[9]) return;
  int e = 0;
  #pragma unroll
  for(int i = 1; i <= 8; i++) if(rowTile >= aoff[i]) e = i;
  __shared__ __align__(16) u16 As0[2048], As1[2048], Bs0[4096], Bs1[4096];
  const int tid = threadIdx.x, lane = tid & 63, wid = tid >> 6;
  const int wm = wid >> 1, wn = wid & 1;                 // wave tile 32x64
  const int tn = bx * 128;
  const u16* Bt = W2T + (size_t)e * E_ * DFF_;

  const int ksw = KSW32(lane);
  const u16* gA = ehid + (size_t)(rowTile + wid*16 + (lane >> 2)) * DFF_ + ksw;
  const u16* gB0 = Bt + (size_t)(tn + wid*32 + (lane >> 2)) * DFF_ + ksw;
  const u16* gB1 = gB0 + (size_t)16 * DFF_;
  u16* lA  = As0 + wid*512;  u16* lAb = As1 + wid*512;
  u16* lB0 = Bs0 + wid*1024; u16* lB1 = lB0 + 512;
  u16* lB0b = Bs1 + wid*1024; u16* lB1b = lB0b + 512;
  const int fo = FRAGOFF(lane);
  const int fA = wm * 1024, fB = wn * 2048;

  const f32x4 zero = {0.f,0.f,0.f,0.f};
  f32x4 acc[2][4];
  #pragma unroll
  for(int m = 0; m < 2; m++)
    #pragma unroll
    for(int n = 0; n < 4; n++) acc[m][n] = zero;

  for(int k0 = 0; k0 < DFF_; k0 += 64){
    __syncthreads();
    gl_lds16(gA + k0, lA);
    gl_lds16(gB0 + k0, lB0); gl_lds16(gB1 + k0, lB1);
    gl_lds16(gA + k0+32, lAb);
    gl_lds16(gB0 + k0+32, lB0b); gl_lds16(gB1 + k0+32, lB1b);
    __syncthreads();
    bf16x8 aF[2], bF[4];
    #pragma unroll
    for(int m = 0; m < 2; m++) aF[m] = *(const bf16x8*)(As0 + fA + m*512 + fo);
    #pragma unroll
    for(int n = 0; n < 4; n++) bF[n] = *(const bf16x8*)(Bs0 + fB + n*512 + fo);
    #pragma unroll
    for(int m = 0; m < 2; m++)
      #pragma unroll
      for(int n = 0; n < 4; n++)
        acc[m][n] = __builtin_amdgcn_mfma_f32_16x16x32_bf16(aF[m], bF[n], acc[m][n], 0, 0, 0);
    #pragma unroll
    for(int m = 0; m < 2; m++) aF[m] = *(const bf16x8*)(As1 + fA + m*512 + fo);
    #pragma unroll
    for(int n = 0; n < 4; n++) bF[n] = *(const bf16x8*)(Bs1 + fB + n*512 + fo);
    #pragma unroll
    for(int m = 0; m < 2; m++)
      #pragma unroll
      for(int n = 0; n < 4; n++)
        acc[m][n] = __builtin_amdgcn_mfma_f32_16x16x32_bf16(aF[m], bF[n], acc[m][n], 0, 0, 0);
  }
  #pragma unroll
  for(int m = 0; m < 2; m++){
    const int row = rowTile + wm*32 + m*16 + ((lane >> 4) << 2);
    #pragma unroll
    for(int r = 0; r < 4; r++){
      const int rr = row + r;
      const int tok = rowlist[rr];
      if(tok < 0) continue;
      const float g = rowgate[rr];
      #pragma unroll
      for(int n = 0; n < 4; n++){
        const int col = tn + wn*64 + n*16 + (lane & 15);
        atomicAdd(&outF[(size_t)tok * E_ + col], g * (acc[m][n][r] + b9dn[e * E_ + col]));
      }
    }
  }
}

extern "C" void kernel_launch(void* const* d_in, const int* in_sizes, int n_in,
                              void* d_out, int out_size, void* d_ws, size_t ws_size,
                              hipStream_t stream)
{
  (void)in_sizes; (void)n_in; (void)out_size;
  const float* x    = (const float*)d_in[0];
  const float* ln1g = (const float*)d_in[1];
  const float* ln1b = (const float*)d_in[2];
  const float* wq   = (const float*)d_in[3];
  const float* bq   = (const float*)d_in[4];
  const float* wk   = (const float*)d_in[5];
  const float* bk   = (const float*)d_in[6];
  const float* wv   = (const float*)d_in[7];
  const float* bv   = (const float*)d_in[8];
  const float* wo   = (const float*)d_in[9];
  const float* bo   = (const float*)d_in[10];
  const float* ln2g = (const float*)d_in[11];
  const float* ln2b = (const float*)d_in[12];
  const float* sw1  = (const float*)d_in[13];
  const float* sb1  = (const float*)d_in[14];
  const float* sw2  = (const float*)d_in[15];
  const float* sb2  = (const float*)d_in[16];
  const float* ew1  = (const float*)d_in[17];
  const float* eb1  = (const float*)d_in[18];
  const float* ew2  = (const float*)d_in[19];
  const float* eb2  = (const float*)d_in[20];
  const float* wgate= (const float*)d_in[21];
  float* out = (float*)d_out;
  char* ws = (char*)d_ws;
  const size_t MB = 1024ull * 1024ull;
  const bool big = (ws_size >= 194 * MB);

  // router/scalar block pointers (offset chosen per path)
  char* rt = big ? (ws + 192*MB) : (ws + 24*MB);
  float* probs   = (float*)(rt);
  float* tkgate  = (float*)(rt + 131072);
  int*   tkidx   = (int*)  (rt + 163840);
  int*   counts  = (int*)  (rt + 196608);
  int*   aoff    = (int*)  (rt + 196672);
  int*   rowlist = (int*)  (rt + 196800);
  float* rowgate = (float*)(rt + 250560);
  float* bcat    = (float*)(rt + 304320);
  float* b9up    = (float*)(rt + 316608);
  float* b9dn    = (float*)(rt + 464064);

  if(big){
    // ---- unified layout (needs 193MB) ----
    u16* h    = (u16*)(ws + 0);        // 8MB   (dead after qkv)
    u16* qkvb = (u16*)(ws + 8*MB);     // 24MB  (dead after attn)
    u16* ctx  = (u16*)(ws + 32*MB);    // 8MB   (dead after o-proj)
    u16* wT4  = (u16*)(ws + 40*MB);    // 8MB   (dead after o-proj)
    u16* ehid = (u16*)(ws + 0);        // 105MB (written by upmoe, over dead attn-phase bufs)
    u16* W1T  = (u16*)(ws + 112*MB);   // 72MB = 9 panels; later re-used as W2T
    u16* W2T  = W1T;
    u16* h2   = (u16*)(ws + 184*MB);   // 8MB

    prep_kernel<<<64, 256, 0, stream>>>(bq, bk, bv, bcat, counts, rowlist, eb1, sb1, b9up, eb2, sb2, b9dn);
    transpose4_kernel<<<dim3(16,16,4), 256, 0, stream>>>(wq, wk, wv, wo, wT4);
    transpose9_kernel<<<dim3(16,64,9), 256, 0, stream>>>(ew1, sw1, W1T, E_, DFF_);
    ln_kernel<<<NT_, 256, 0, stream>>>(x, ln1g, ln1b, h);
    gemm_kernel<0><<<dim3(24,32), 256, 0, stream>>>(h, wT4, QS_, E_, bcat, qkvb);
    attn_kernel<<<dim3(16,64), 256, 0, stream>>>(qkvb, ctx);
    gemm64_kernel<2><<<dim3(8,64), 256, 0, stream>>>(ctx, wT4 + 3u*1024*1024, E_, E_, bo, out, x);
    ln_router_kernel<<<NT_, 256, 0, stream>>>(out, ln2g, ln2b, h2, wgate, probs, tkgate, tkidx, counts);
    route_kernel<<<1, 256, 0, stream>>>(counts, tkidx, tkgate, probs, aoff, rowlist, rowgate,
                                        out + (size_t)NT_ * E_, 1);
    upmoe_kernel<<<dim3(32,104), 256, 0, stream>>>(h2, W1T, b9up, rowlist, aoff, ehid);
    transpose9_kernel<<<dim3(64,16,9), 256, 0, stream>>>(ew2, sw2, W2T, DFF_, E_);
    downmoe_kernel<<<dim3(8,208), 256, 0, stream>>>(ehid, W2T, b9dn, rowlist, rowgate, aoff, out);
  } else {
    // ---- legacy serial layout (<=168MB) ----
    u16* h    = (u16*)(ws + 0);
    u16* h2   = (u16*)(ws + 8*MB);
    u16* wT4  = (u16*)(ws + 16*MB);
    u16* swT  = wT4;
    u16* qkvb = (u16*)(ws + 32*MB);
    u16* ctx  = (u16*)(ws + 56*MB);
    u16* hidS = (u16*)(ws + 64*MB);
    u16* ewT  = (u16*)(ws + 32*MB);
    u16* ehid = (u16*)(ws + 96*MB);

    prep_kernel<<<64, 256, 0, stream>>>(bq, bk, bv, bcat, counts, rowlist, eb1, sb1, b9up, eb2, sb2, b9dn);
    transpose4_kernel<<<dim3(16,16,4), 256, 0, stream>>>(wq, wk, wv, wo, wT4);
    ln_kernel<<<NT_, 256, 0, stream>>>(x, ln1g, ln1b, h);
    gemm_kernel<0><<<dim3(24,32), 256, 0, stream>>>(h, wT4, QS_, E_, bcat, qkvb);
    attn_kernel<<<dim3(16,64), 256, 0, stream>>>(qkvb, ctx);
    gemm64_kernel<2><<<dim3(8,64), 256, 0, stream>>>(ctx, wT4 + 3u*1024*1024, E_, E_, bo, out, x);
    ln_router_kernel<<<NT_, 256, 0, stream>>>(out, ln2g, ln2b, h2, wgate, probs, tkgate, tkidx, counts);
    transpose_kernel<<<dim3(16,64), 256, 0, stream>>>(sw1, swT, E_, DFF_);
    gemm_kernel<1><<<dim3(32,32), 256, 0, stream>>>(h2, swT, DFF_, E_, sb1, hidS);
    transpose_kernel<<<dim3(64,16), 256, 0, stream>>>(sw2, swT, DFF_, E_);
    gemm64_kernel<3><<<dim3(8,64), 256, 0, stream>>>(hidS, swT, E_, DFF_, sb2, out, nullptr);
    route_kernel<<<1, 256, 0, stream>>>(counts, tkidx, tkgate, probs, aoff, rowlist, rowgate,
                                        out + (size_t)NT_ * E_, 0);
    transpose9_kernel<<<dim3(16,64,8), 256, 0, stream>>>(ew1, sw1, ewT, E_, DFF_);
    upmoe_kernel<<<dim3(32,104), 256, 0, stream>>>(h2, ewT, b9up, rowlist, aoff, ehid);
    transpose9_kernel<<<dim3(64,16,8), 256, 0, stream>>>(ew2, sw2, ewT, DFF_, E_);
    downmoe_kernel<<<dim3(8,208), 256, 0, stream>>>(ehid, ewT, b9dn, rowlist, rowgate, aoff, out);
  }
}